// Round 9
// baseline (6438.169 us; speedup 1.0000x reference)
//
#include <hip/hip_runtime.h>
#include <math.h>

#define PI2 6.2831853071795864769f

typedef short bf16x8 __attribute__((ext_vector_type(8)));
typedef float f32x4 __attribute__((ext_vector_type(4)));
typedef int   i32x4 __attribute__((ext_vector_type(4)));

// ---------------------------------------------------------------- helpers
__device__ inline unsigned splitf(float v) {
    unsigned u  = __float_as_uint(v);
    unsigned r  = (u + 0x7fffu + ((u >> 16) & 1u)) >> 16;
    float hi    = __uint_as_float(r << 16);
    float lof   = v - hi;
    unsigned u2 = __float_as_uint(lof);
    unsigned r2 = (u2 + 0x7fffu + ((u2 >> 16) & 1u)) >> 16;
    return (r & 0xffffu) | (r2 << 16);
}
__device__ inline float upk(unsigned w) {
    return __uint_as_float(w << 16) + __uint_as_float(w & 0xffff0000u);
}

union VecU { i32x4 i; bf16x8 s; };

__device__ inline void unpack2(i32x4 d0, i32x4 d1, bf16x8& hi, bf16x8& lo) {
    VecU h, l;
    h.i.x = __builtin_amdgcn_perm(d0.y, d0.x, 0x05040100);
    h.i.y = __builtin_amdgcn_perm(d0.w, d0.z, 0x05040100);
    h.i.z = __builtin_amdgcn_perm(d1.y, d1.x, 0x05040100);
    h.i.w = __builtin_amdgcn_perm(d1.w, d1.z, 0x05040100);
    l.i.x = __builtin_amdgcn_perm(d0.y, d0.x, 0x07060302);
    l.i.y = __builtin_amdgcn_perm(d0.w, d0.z, 0x07060302);
    l.i.z = __builtin_amdgcn_perm(d1.y, d1.x, 0x07060302);
    l.i.w = __builtin_amdgcn_perm(d1.w, d1.z, 0x07060302);
    hi = h.s; lo = l.s;
}

__device__ inline void unpack8(const int* d, bf16x8& hi, bf16x8& lo) {
    VecU h, l;
    h.i.x = __builtin_amdgcn_perm(d[1], d[0], 0x05040100);
    h.i.y = __builtin_amdgcn_perm(d[3], d[2], 0x05040100);
    h.i.z = __builtin_amdgcn_perm(d[5], d[4], 0x05040100);
    h.i.w = __builtin_amdgcn_perm(d[7], d[6], 0x05040100);
    l.i.x = __builtin_amdgcn_perm(d[1], d[0], 0x07060302);
    l.i.y = __builtin_amdgcn_perm(d[3], d[2], 0x07060302);
    l.i.z = __builtin_amdgcn_perm(d[5], d[4], 0x07060302);
    l.i.w = __builtin_amdgcn_perm(d[7], d[6], 0x07060302);
    hi = h.s; lo = l.s;
}

// ---------------------------------------------------------------- sentinel
__global__ void sentinel_kernel(float* __restrict__ out, int n) {
    int t = blockIdx.x * 256 + threadIdx.x;
    if (t < n) out[t] = 12345.0f;
}

// ---------------------------------------------------------------- split (weights)
__global__ void split_kernel(const float* __restrict__ in, unsigned* __restrict__ out) {
    long q = (long)blockIdx.x * 256 + threadIdx.x;
    const float4* ip = (const float4*)in;
    float4 v = ip[q];
    i32x4 o;
    o.x = (int)splitf(v.x); o.y = (int)splitf(v.y);
    o.z = (int)splitf(v.z); o.w = (int)splitf(v.w);
    ((i32x4*)out)[q] = o;
}

// ---------------------------------------------------------------- encoder: h in SPLIT format
__global__ void enc_kernel(const float* __restrict__ x, const float* __restrict__ w,
                           const float* __restrict__ b, const float* __restrict__ pos,
                           unsigned* __restrict__ h) {
    long t = (long)blockIdx.x * 256 + threadIdx.x;   // quad index
    int pq = (int)(t & 16383);
    int c  = (int)((t >> 14) & 127);
    int bb = (int)(t >> 21);
    float4 x0 = *(const float4*)(x + ((long)bb * 2 + 0) * 65536 + pq * 4);
    float4 x1 = *(const float4*)(x + ((long)bb * 2 + 1) * 65536 + pq * 4);
    float4 pv = *(const float4*)(pos + (long)c * 65536 + pq * 4);
    float w0 = w[c * 2], w1 = w[c * 2 + 1], bc = b[c];
    uint4 o;
    o.x = splitf((w0 * x0.x + w1 * x1.x + bc) * 8.0f + pv.x);
    o.y = splitf((w0 * x0.y + w1 * x1.y + bc) * 8.0f + pv.y);
    o.z = splitf((w0 * x0.z + w1 * x1.z + bc) * 8.0f + pv.z);
    o.w = splitf((w0 * x0.w + w1 * x1.w + bc) * 8.0f + pv.w);
    *(uint4*)(h + t * 4) = o;
}

// ---------------------------------------------------------------- fused MLP: t2 = W2*silu(W1*h+b1)+b2
// WAVE-INDEPENDENT partition: each wave owns 16 px for BOTH gemms (gemm1: all 64
// hid of the chunk for its px; gemm2: all 128 n for its px). Hidden buffer is
// wave-PRIVATE -> zero chunk barriers (was 16). Only the A-stage syncthreads
// remains; waves drift freely across chunks (cross-wave MFMA/VALU/LDS overlap).
// Epilogue reuses the wave's own (dead) A rows as a private transpose buffer --
// also barrier-free. LDS: A[64][132] 33792B + 4x H[16][68] 17408B = 51200B.
__global__ __launch_bounds__(256, 3)
void mlp_fused(const unsigned* __restrict__ Ax, const unsigned* __restrict__ W1x,
               const float* __restrict__ b1, const unsigned* __restrict__ W2x,
               const float* __restrict__ b2, float* __restrict__ t2) {
    __shared__ unsigned SM[12800];
    unsigned* ALDS = SM;                       // A[px64][132] packed-split dwords
    int tid = threadIdx.x;
    int w = tid >> 6, l = tid & 63;
    int lr = l & 15, lg = l >> 4;
    int p0 = blockIdx.x * 64;
    unsigned* HW = SM + 8448 + w * 1088;       // wave-private hidden [16][68]

    // ---- stage A (split h) into LDS, transposed to px-major (coalesced uint4)
#pragma unroll
    for (int i = 0; i < 8; i++) {
        int f = i * 256 + tid;           // 0..2047
        int k = f >> 4, q = f & 15;      // k: 0..127 ch, q: 0..15 px-quad
        uint4 v = *(const uint4*)(Ax + (long)k * 65536 + p0 + q * 4);
        ALDS[(q * 4 + 0) * 132 + k] = v.x;
        ALDS[(q * 4 + 1) * 132 + k] = v.y;
        ALDS[(q * 4 + 2) * 132 + k] = v.z;
        ALDS[(q * 4 + 3) * 132 + k] = v.w;
    }
    __syncthreads();                     // the ONLY barrier in this kernel

    f32x4 acc2[8] = {};                  // [n-tile 0..7], M=16 own px
#pragma unroll 1
    for (int c = 0; c < 8; c++) {
        // ---- gemm1: own 16 px x 64 hid (chunk c), K=128
        f32x4 acc1[4] = {};
#pragma unroll
        for (int ks = 0; ks < 4; ks++) {
            const i32x4* apx = (const i32x4*)&ALDS[(w * 16 + lr) * 132 + ks * 32 + lg * 8];
            i32x4 a0 = apx[0], a1 = apx[1];
            bf16x8 ah, al; unpack2(a0, a1, ah, al);
#pragma unroll
            for (int ns = 0; ns < 4; ns++) {
                const unsigned* bp = W1x + (c * 64 + ns * 16 + lr) * 128 + ks * 32 + lg * 8;
                i32x4 d0 = *(const i32x4*)bp;
                i32x4 d1 = *(const i32x4*)(bp + 4);
                bf16x8 bh, bl; unpack2(d0, d1, bh, bl);
                acc1[ns] = __builtin_amdgcn_mfma_f32_16x16x32_bf16(ah, bh, acc1[ns], 0, 0, 0);
                acc1[ns] = __builtin_amdgcn_mfma_f32_16x16x32_bf16(ah, bl, acc1[ns], 0, 0, 0);
                acc1[ns] = __builtin_amdgcn_mfma_f32_16x16x32_bf16(al, bh, acc1[ns], 0, 0, 0);
            }
        }
        // ---- silu + split -> wave-private HW[px16][68]; lane: hid=ns*16+lr, px=lg*4+r
#pragma unroll
        for (int ns = 0; ns < 4; ns++) {
            float bias = b1[c * 64 + ns * 16 + lr];
#pragma unroll
            for (int r = 0; r < 4; r++) {
                float pre = acc1[ns][r] + bias;
                float s = pre / (1.0f + __expf(-pre));
                HW[(lg * 4 + r) * 68 + ns * 16 + lr] = splitf(s);
            }
        }
        // no barrier: same-wave ds ordering is in-issue-order; compiler waits lgkm
        // ---- gemm2 partial: own 16 px x all 128 n, K=64 (chunk c)
#pragma unroll
        for (int ks2 = 0; ks2 < 2; ks2++) {
            const i32x4* hp = (const i32x4*)&HW[lr * 68 + ks2 * 32 + lg * 8];
            i32x4 h0 = hp[0], h1 = hp[1];
            bf16x8 ah, al; unpack2(h0, h1, ah, al);
#pragma unroll
            for (int ns = 0; ns < 8; ns++) {
                const unsigned* bp = W2x + (ns * 16 + lr) * 512 + c * 64 + ks2 * 32 + lg * 8;
                i32x4 d0 = *(const i32x4*)bp;
                i32x4 d1 = *(const i32x4*)(bp + 4);
                bf16x8 bh, bl; unpack2(d0, d1, bh, bl);
                acc2[ns] = __builtin_amdgcn_mfma_f32_16x16x32_bf16(ah, bh, acc2[ns], 0, 0, 0);
                acc2[ns] = __builtin_amdgcn_mfma_f32_16x16x32_bf16(ah, bl, acc2[ns], 0, 0, 0);
                acc2[ns] = __builtin_amdgcn_mfma_f32_16x16x32_bf16(al, bh, acc2[ns], 0, 0, 0);
            }
        }
    }
    // ---- epilogue (barrier-free): transpose via the wave's OWN dead A rows.
    // T4 region = ALDS rows [w*16 .. w*16+16) = 2112 dw >= 2048 dw needed.
    float4* T4 = (float4*)(ALDS + (long)w * 16 * 132);   // [n=128][pxq=4] float4 slots
#pragma unroll
    for (int ns = 0; ns < 8; ns++) {
        int n = ns * 16 + lr;
        float bias = b2[n];
        float4 v;
        v.x = acc2[ns][0] + bias;
        v.y = acc2[ns][1] + bias;
        v.z = acc2[ns][2] + bias;
        v.w = acc2[ns][3] + bias;
        T4[n * 4 + lg] = v;              // acc2 rows are 4 consecutive px
    }
#pragma unroll
    for (int it = 0; it < 8; it++) {
        int f = it * 64 + l;             // 0..511 float4s of this wave
        int n = f >> 2, q = f & 3;
        float4 v = T4[n * 4 + q];
        *(float4*)(t2 + (long)n * 65536 + p0 + w * 16 + q * 4) = v;
    }
}

// ---------------------------------------------------------------- OXO: h += t2*W^T + b (h split)
__global__ __launch_bounds__(256, 2)
void oxo_kernel(const unsigned* __restrict__ Tx, const unsigned* __restrict__ Bx,
                const float* __restrict__ ob, unsigned* __restrict__ h) {
    __shared__ float T[128 * 128];
    int tid = threadIdx.x;
    int w = tid >> 6, l = tid & 63;
    int lr = l & 15, lg = l >> 4;
    int m0 = blockIdx.x * 128;
    int n0 = w * 32;
    f32x4 acc[8][2] = {};
    for (int k0 = 0; k0 < 128; k0 += 32) {
        bf16x8 bh[2], bl[2];
#pragma unroll
        for (int ns = 0; ns < 2; ns++) {
            const unsigned* bp = Bx + (n0 + ns * 16 + lr) * 128 + k0 + lg * 8;
            i32x4 d0 = *(const i32x4*)bp;
            i32x4 d1 = *(const i32x4*)(bp + 4);
            unpack2(d0, d1, bh[ns], bl[ns]);
        }
#pragma unroll
        for (int ms = 0; ms < 8; ms++) {
            const unsigned* ap = Tx + (long)(k0 + lg * 8) * 65536 + m0 + ms * 16 + lr;
            int d[8];
#pragma unroll
            for (int j = 0; j < 8; j++) d[j] = (int)ap[(long)j * 65536];
            bf16x8 ah, al; unpack8(d, ah, al);
#pragma unroll
            for (int ns = 0; ns < 2; ns++) {
                acc[ms][ns] = __builtin_amdgcn_mfma_f32_16x16x32_bf16(ah, bh[ns], acc[ms][ns], 0, 0, 0);
                acc[ms][ns] = __builtin_amdgcn_mfma_f32_16x16x32_bf16(ah, bl[ns], acc[ms][ns], 0, 0, 0);
                acc[ms][ns] = __builtin_amdgcn_mfma_f32_16x16x32_bf16(al, bh[ns], acc[ms][ns], 0, 0, 0);
            }
        }
    }
#pragma unroll
    for (int ns = 0; ns < 2; ns++) {
        int n = n0 + ns * 16 + lr;
#pragma unroll
        for (int ms = 0; ms < 8; ms++) {
            int blk = ((ms * 4 + lg) + n) & 31;
#pragma unroll
            for (int r = 0; r < 4; r++)
                T[n * 128 + blk * 4 + r] = acc[ms][ns][r];
        }
    }
    __syncthreads();
#pragma unroll
    for (int i = 0; i < 16; i++) {
        int flat = i * 256 + tid;
        int n = flat >> 5, q = flat & 31;
        const float4* src = (const float4*)&T[n * 128 + (((q + n) & 31) * 4)];
        float4 v = *src;
        float bias = ob[n];
        unsigned* hp = h + (long)n * 65536 + m0 + q * 4;
        uint4 hv = *(uint4*)hp;
        uint4 o;
        o.x = splitf(upk(hv.x) + v.x + bias);
        o.y = splitf(upk(hv.y) + v.y + bias);
        o.z = splitf(upk(hv.z) + v.z + bias);
        o.w = splitf(upk(hv.w) + v.w + bias);
        *(uint4*)hp = o;
    }
}

// ---------------------------------------------------------------- row forward rfft, CHANNEL-PAIR packed
// z = ch_a + i*ch_b -> one 256-pt FFT per row covers two channels.
// F_a[k] = 0.5*(Z[k]+conj(Z[-k])), F_b[k] = -0.5i*(Z[k]-conj(Z[-k])).
// freq layout per channel: [img64][kt17][y256][kxl8] float2
__global__ void fft_row_fwd(const float* __restrict__ in, float2* __restrict__ freq, int c0) {
    __shared__ float2 A[4][256];
    __shared__ float2 B[4][256];
    __shared__ float2 TW[128];
    int tid = threadIdx.x;
    int pr = blockIdx.x >> 6, rgrp = blockIdx.x & 63;   // pr: channel pair 0..31
    if (tid < 128) {
        float sn, cs; __sincosf((PI2 / 256.f) * (float)tid, &sn, &cs);
        TW[tid] = make_float2(cs, sn);
    }
    {
        int r = tid >> 6, l = tid & 63;
        int row = rgrp * 4 + r;
        const float4* sa = (const float4*)(in + ((long)(c0 + pr * 2 + 0) * 256 + row) * 256);
        const float4* sb = (const float4*)(in + ((long)(c0 + pr * 2 + 1) * 256 + row) * 256);
        float4 va = sa[l], vb = sb[l];
        A[r][l * 4 + 0] = make_float2(va.x, vb.x);
        A[r][l * 4 + 1] = make_float2(va.y, vb.y);
        A[r][l * 4 + 2] = make_float2(va.z, vb.z);
        A[r][l * 4 + 3] = make_float2(va.w, vb.w);
    }
    __syncthreads();
    float2 (*s)[256] = A; float2 (*d)[256] = B;
    for (int m = 1; m < 256; m <<= 1) {
#pragma unroll
        for (int q = 0; q < 2; q++) {
            int bf = tid + q * 256;
            int r = bf >> 7, i = bf & 127;
            int jm = i & ~(m - 1);
            float2 c0v = s[r][i], c1 = s[r][i + 128];
            float2 t = TW[jm];
            float2 df = make_float2(c0v.x - c1.x, c0v.y - c1.y);
            d[r][i + jm]     = make_float2(c0v.x + c1.x, c0v.y + c1.y);
            d[r][i + jm + m] = make_float2(t.x * df.x + t.y * df.y, t.x * df.y - t.y * df.x);
        }
        __syncthreads();
        float2 (*tmp)[256] = s; s = d; d = tmp;
    }
    long iba = (long)(pr * 2 + 0) * 34816;
    long ibb = (long)(pr * 2 + 1) * 34816;
    for (int q = tid; q < 4 * 129; q += 256) {
        int r = q / 129; int k = q - r * 129;
        float2 z  = s[r][k];
        float2 zm = s[r][(256 - k) & 255];
        float2 za = make_float2(0.5f * (z.x + zm.x), 0.5f * (z.y - zm.y));
        float2 zb = make_float2(0.5f * (z.y + zm.y), 0.5f * (zm.x - z.x));
        long off = (k >> 3) * 2048 + (rgrp * 4 + r) * 8 + (k & 7);
        freq[iba + off] = za;
        freq[ibb + off] = zb;
    }
}

// ---------------------------------------------------------------- column FFT + filter + inverse (tiled freq)
__global__ void fft_col(float2* __restrict__ freq, const float* __restrict__ mags,
                        const float* __restrict__ phases, int c0) {
    __shared__ float2 A[8][256];
    __shared__ float2 B[8][256];
    __shared__ float2 TW[128];
    int tid = threadIdx.x;
    int img = blockIdx.x / 17;
    int kt  = blockIdx.x % 17;
    int kx0 = kt * 8;
    float2* base = freq + (long)img * 34816 + kt * 2048;
    if (tid < 128) {
        float sn, cs; __sincosf((PI2 / 256.f) * (float)tid, &sn, &cs);
        TW[tid] = make_float2(cs, sn);
    }
#pragma unroll
    for (int q = 0; q < 8; q++) {
        int e = tid + q * 256;
        A[e & 7][e >> 3] = base[e];       // fully contiguous 16 KB
    }
    __syncthreads();
    float2 (*s)[256] = A; float2 (*d)[256] = B;
    for (int m = 1; m < 256; m <<= 1) {           // forward
#pragma unroll
        for (int q = 0; q < 4; q++) {
            int bf = tid + q * 256;
            int cl = bf >> 7, i = bf & 127;
            int jm = i & ~(m - 1);
            float2 c0v = s[cl][i], c1 = s[cl][i + 128];
            float2 t = TW[jm];
            float2 df = make_float2(c0v.x - c1.x, c0v.y - c1.y);
            d[cl][i + jm]     = make_float2(c0v.x + c1.x, c0v.y + c1.y);
            d[cl][i + jm + m] = make_float2(t.x * df.x + t.y * df.y, t.x * df.y - t.y * df.x);
        }
        __syncthreads();
        float2 (*tmp)[256] = s; s = d; d = tmp;
    }
#pragma unroll
    for (int q = 0; q < 8; q++) {
        int e = tid + q * 256;
        int cl = e & 7, ky = e >> 3;
        int kx = kx0 + cl;
        float2 v = s[cl][ky];
        float2 r = make_float2(0.f, 0.f);
        if (kx < 129) {
            int ry = ky < 128 ? ky : ky - 256;
            if (kx * kx + ry * ry <= 16384) {
                long fi = ((long)(c0 + img) * 256 + ky) * 129 + kx;
                float mg = mags[fi], ph = phases[fi];
                float sg = 1.0f / (1.0f + __expf(-mg));
                float sn, cs; __sincosf(ph, &sn, &cs);
                float fr = sg * cs, fim = sg * sn;
                r = make_float2(v.x * fr - v.y * fim, v.x * fim + v.y * fr);
            }
        }
        s[cl][ky] = r;
    }
    __syncthreads();
    for (int m = 1; m < 256; m <<= 1) {           // inverse
#pragma unroll
        for (int q = 0; q < 4; q++) {
            int bf = tid + q * 256;
            int cl = bf >> 7, i = bf & 127;
            int jm = i & ~(m - 1);
            float2 c0v = s[cl][i], c1 = s[cl][i + 128];
            float2 t = TW[jm];
            float2 df = make_float2(c0v.x - c1.x, c0v.y - c1.y);
            d[cl][i + jm]     = make_float2(c0v.x + c1.x, c0v.y + c1.y);
            d[cl][i + jm + m] = make_float2(t.x * df.x - t.y * df.y, t.x * df.y + t.y * df.x);
        }
        __syncthreads();
        float2 (*tmp)[256] = s; s = d; d = tmp;
    }
#pragma unroll
    for (int q = 0; q < 8; q++) {
        int e = tid + q * 256;
        base[e] = s[e & 7][e >> 3];
    }
}

// ---------------------------------------------------------------- row inverse rfft, CHANNEL-PAIR packed
// Z'[k] = G_a[k] + i*G_b[k] (Hermitian-extended) -> one inverse FFT; Re->a, Im->b.
// CRITICAL: numpy irfft (pocketfft c2r) IGNORES the imaginary parts of the DC and
// Nyquist bins. Zero them on load or channel b's Im(DC/Nyq) leaks into channel a.
__global__ void fft_row_inv(const float2* __restrict__ freq, unsigned* __restrict__ out, int c0) {
    __shared__ float2 A[4][256];
    __shared__ float2 B[4][256];
    __shared__ float2 TW[128];
    int tid = threadIdx.x;
    int pr = blockIdx.x >> 6, rgrp = blockIdx.x & 63;
    if (tid < 128) {
        float sn, cs; __sincosf((PI2 / 256.f) * (float)tid, &sn, &cs);
        TW[tid] = make_float2(cs, sn);
    }
    long iba = (long)(pr * 2 + 0) * 34816;
    long ibb = (long)(pr * 2 + 1) * 34816;
#pragma unroll
    for (int q = 0; q < 4; q++) {
        int e = tid + q * 256;
        int r = e >> 8, xx = e & 255;
        int k = (xx <= 128) ? xx : 256 - xx;
        long off = (k >> 3) * 2048 + (rgrp * 4 + r) * 8 + (k & 7);
        float2 ga = freq[iba + off];
        float2 gb = freq[ibb + off];
        if (k == 0 || k == 128) { ga.y = 0.f; gb.y = 0.f; }   // irfft c2r semantics
        float2 v;
        if (xx <= 128) v = make_float2(ga.x - gb.y, ga.y + gb.x);          // Ga + i*Gb
        else           v = make_float2(ga.x + gb.y, gb.x - ga.y);          // conj(Ga) + i*conj(Gb)
        A[r][xx] = v;
    }
    __syncthreads();
    float2 (*s)[256] = A; float2 (*d)[256] = B;
    for (int m = 1; m < 256; m <<= 1) {
#pragma unroll
        for (int q = 0; q < 2; q++) {
            int bf = tid + q * 256;
            int r = bf >> 7, i = bf & 127;
            int jm = i & ~(m - 1);
            float2 c0v = s[r][i], c1 = s[r][i + 128];
            float2 t = TW[jm];
            float2 df = make_float2(c0v.x - c1.x, c0v.y - c1.y);
            d[r][i + jm]     = make_float2(c0v.x + c1.x, c0v.y + c1.y);
            d[r][i + jm + m] = make_float2(t.x * df.x - t.y * df.y, t.x * df.y + t.y * df.x);
        }
        __syncthreads();
        float2 (*tmp)[256] = s; s = d; d = tmp;
    }
    {
        int r = tid >> 6, l = tid & 63;
        const float sc = 1.0f / 65536.0f;
        int row = rgrp * 4 + r;
        uint4 oa, ob;
        oa.x = splitf(s[r][l * 4 + 0].x * sc);
        oa.y = splitf(s[r][l * 4 + 1].x * sc);
        oa.z = splitf(s[r][l * 4 + 2].x * sc);
        oa.w = splitf(s[r][l * 4 + 3].x * sc);
        ob.x = splitf(s[r][l * 4 + 0].y * sc);
        ob.y = splitf(s[r][l * 4 + 1].y * sc);
        ob.z = splitf(s[r][l * 4 + 2].y * sc);
        ob.w = splitf(s[r][l * 4 + 3].y * sc);
        *(uint4*)(out + ((long)(c0 + pr * 2 + 0) * 256 + row) * 256 + l * 4) = oa;
        *(uint4*)(out + ((long)(c0 + pr * 2 + 1) * 256 + row) * 256 + l * 4) = ob;
    }
}

// ---------------------------------------------------------------- decoder (h split)
__global__ void dec_kernel(const unsigned* __restrict__ h, const float* __restrict__ w,
                           const float* __restrict__ b, float* __restrict__ out) {
    int t = blockIdx.x * 256 + threadIdx.x;
    int bb = t >> 16, p = t & 65535;
    const unsigned* hb = h + (long)bb * 8388608 + p;
    float a0 = b[0], a1 = b[1];
    float a0b = 0.f, a1b = 0.f;
#pragma unroll 4
    for (int c = 0; c < 128; c += 2) {
        float h0 = upk(hb[(long)c * 65536]);
        float h1 = upk(hb[(long)(c + 1) * 65536]);
        a0  += w[c] * h0;        a1  += w[128 + c] * h0;
        a0b += w[c + 1] * h1;    a1b += w[128 + c + 1] * h1;
    }
    out[((long)bb * 2 + 0) * 65536 + p] = (a0 + a0b) * 0.125f;
    out[((long)bb * 2 + 1) * 65536 + p] = (a1 + a1b) * 0.125f;
}

// ---------------------------------------------------------------- launch
extern "C" void kernel_launch(void* const* d_in, const int* in_sizes, int n_in,
                              void* d_out, int out_size, void* d_ws, size_t ws_size,
                              hipStream_t stream) {
    const float* x        = (const float*)d_in[0];
    const float* enc_w    = (const float*)d_in[1];
    const float* enc_b    = (const float*)d_in[2];
    const float* pos_emb  = (const float*)d_in[3];
    const float* mlp_w1   = (const float*)d_in[4];
    const float* mlp_b1   = (const float*)d_in[5];
    const float* mlp_w2   = (const float*)d_in[6];
    const float* mlp_b2   = (const float*)d_in[7];
    const float* spec_mag = (const float*)d_in[8];
    const float* spec_ph  = (const float*)d_in[9];
    const float* oxo_w    = (const float*)d_in[10];
    const float* oxo_b    = (const float*)d_in[11];
    const float* dec_w    = (const float*)d_in[12];
    const float* dec_b    = (const float*)d_in[13];
    float* outp = (float*)d_out;

    // ws layout (dwords):
    //  h (split)      33,554,432
    //  t2 / TxO        8,388,608
    //  freq (64ch)     4,456,448   ([img64][kt17][y256][kx8] float2)
    //  Wx1/Wx2/Wox       147,456
    //  total          46,546,944 dw = 186,187,776 B
    const size_t WS_NEEDED = 186187776ULL;
    if (ws_size < WS_NEEDED) {
        sentinel_kernel<<<(out_size + 255) / 256, 256, 0, stream>>>(outp, out_size);
        return;
    }

    unsigned* u    = (unsigned*)d_ws;
    unsigned* h    = u;
    float*    t2   = (float*)(u + 33554432);
    unsigned* TxO  = (unsigned*)t2;
    float2*   freq = (float2*)(u + 41943040);
    unsigned* Wx1  = u + 46399488;
    unsigned* Wx2  = Wx1 + 65536;
    unsigned* Wox  = Wx2 + 65536;

    enc_kernel<<<32768, 256, 0, stream>>>(x, enc_w, enc_b, pos_emb, h);

    for (int l = 0; l < 4; l++) {
        split_kernel<<<64, 256, 0, stream>>>(mlp_w1 + (long)l * 65536, Wx1);
        split_kernel<<<64, 256, 0, stream>>>(mlp_w2 + (long)l * 65536, Wx2);
        split_kernel<<<16, 256, 0, stream>>>(oxo_w + (long)l * 16384, Wox);
        const float* b1l = mlp_b1 + l * 512;
        const float* b2l = mlp_b2 + l * 128;
        const float* mgl = spec_mag + (long)l * 4227072;
        const float* phl = spec_ph  + (long)l * 4227072;
        const float* obl = oxo_b + l * 128;
        for (int b = 0; b < 4; b++) {
            unsigned* hb = h + (long)b * 8388608;
            mlp_fused<<<1024, 256, 0, stream>>>(hb, Wx1, b1l, Wx2, b2l, t2);
            for (int c0 = 0; c0 < 128; c0 += 64) {
                fft_row_fwd<<<2048, 256, 0, stream>>>(t2, freq, c0);
                fft_col<<<64 * 17, 256, 0, stream>>>(freq, mgl, phl, c0);
                fft_row_inv<<<2048, 256, 0, stream>>>(freq, TxO, c0);
            }
            oxo_kernel<<<512, 256, 0, stream>>>(TxO, Wox, obl, hb);
        }
    }

    dec_kernel<<<1024, 256, 0, stream>>>(h, dec_w, dec_b, outp);
}

// Round 10
// 3488.192 us; speedup vs baseline: 1.8457x; 1.8457x over previous
//
#include <hip/hip_runtime.h>
#include <math.h>

#define PI2 6.2831853071795864769f

typedef short bf16x8 __attribute__((ext_vector_type(8)));
typedef float f32x4 __attribute__((ext_vector_type(4)));
typedef int   i32x4 __attribute__((ext_vector_type(4)));

// ---------------------------------------------------------------- helpers
__device__ inline unsigned splitf(float v) {
    unsigned u  = __float_as_uint(v);
    unsigned r  = (u + 0x7fffu + ((u >> 16) & 1u)) >> 16;
    float hi    = __uint_as_float(r << 16);
    float lof   = v - hi;
    unsigned u2 = __float_as_uint(lof);
    unsigned r2 = (u2 + 0x7fffu + ((u2 >> 16) & 1u)) >> 16;
    return (r & 0xffffu) | (r2 << 16);
}
__device__ inline float upk(unsigned w) {
    return __uint_as_float(w << 16) + __uint_as_float(w & 0xffff0000u);
}

union VecU { i32x4 i; bf16x8 s; };

__device__ inline void unpack2(i32x4 d0, i32x4 d1, bf16x8& hi, bf16x8& lo) {
    VecU h, l;
    h.i.x = __builtin_amdgcn_perm(d0.y, d0.x, 0x05040100);
    h.i.y = __builtin_amdgcn_perm(d0.w, d0.z, 0x05040100);
    h.i.z = __builtin_amdgcn_perm(d1.y, d1.x, 0x05040100);
    h.i.w = __builtin_amdgcn_perm(d1.w, d1.z, 0x05040100);
    l.i.x = __builtin_amdgcn_perm(d0.y, d0.x, 0x07060302);
    l.i.y = __builtin_amdgcn_perm(d0.w, d0.z, 0x07060302);
    l.i.z = __builtin_amdgcn_perm(d1.y, d1.x, 0x07060302);
    l.i.w = __builtin_amdgcn_perm(d1.w, d1.z, 0x07060302);
    hi = h.s; lo = l.s;
}

__device__ inline void unpack8(const int* d, bf16x8& hi, bf16x8& lo) {
    VecU h, l;
    h.i.x = __builtin_amdgcn_perm(d[1], d[0], 0x05040100);
    h.i.y = __builtin_amdgcn_perm(d[3], d[2], 0x05040100);
    h.i.z = __builtin_amdgcn_perm(d[5], d[4], 0x05040100);
    h.i.w = __builtin_amdgcn_perm(d[7], d[6], 0x05040100);
    l.i.x = __builtin_amdgcn_perm(d[1], d[0], 0x07060302);
    l.i.y = __builtin_amdgcn_perm(d[3], d[2], 0x07060302);
    l.i.z = __builtin_amdgcn_perm(d[5], d[4], 0x07060302);
    l.i.w = __builtin_amdgcn_perm(d[7], d[6], 0x07060302);
    hi = h.s; lo = l.s;
}

// complex multiply by e^{-i th} (fwd) / e^{+i th} (inv), t = (cos th, sin th)
__device__ inline float2 cmulf(float2 t, float2 v) {
    return make_float2(t.x * v.x + t.y * v.y, t.x * v.y - t.y * v.x);
}
__device__ inline float2 cmuli(float2 t, float2 v) {
    return make_float2(t.x * v.x - t.y * v.y, t.x * v.y + t.y * v.x);
}
__device__ inline float2 cadd(float2 a, float2 b) { return make_float2(a.x + b.x, a.y + b.y); }
__device__ inline float2 csub(float2 a, float2 b) { return make_float2(a.x - b.x, a.y - b.y); }

// ---------------------------------------------------------------- sentinel
__global__ void sentinel_kernel(float* __restrict__ out, int n) {
    int t = blockIdx.x * 256 + threadIdx.x;
    if (t < n) out[t] = 12345.0f;
}

// ---------------------------------------------------------------- split (weights)
__global__ void split_kernel(const float* __restrict__ in, unsigned* __restrict__ out) {
    long q = (long)blockIdx.x * 256 + threadIdx.x;
    const float4* ip = (const float4*)in;
    float4 v = ip[q];
    i32x4 o;
    o.x = (int)splitf(v.x); o.y = (int)splitf(v.y);
    o.z = (int)splitf(v.z); o.w = (int)splitf(v.w);
    ((i32x4*)out)[q] = o;
}

// ---------------------------------------------------------------- encoder: h in SPLIT format
__global__ void enc_kernel(const float* __restrict__ x, const float* __restrict__ w,
                           const float* __restrict__ b, const float* __restrict__ pos,
                           unsigned* __restrict__ h) {
    long t = (long)blockIdx.x * 256 + threadIdx.x;   // quad index
    int pq = (int)(t & 16383);
    int c  = (int)((t >> 14) & 127);
    int bb = (int)(t >> 21);
    float4 x0 = *(const float4*)(x + ((long)bb * 2 + 0) * 65536 + pq * 4);
    float4 x1 = *(const float4*)(x + ((long)bb * 2 + 1) * 65536 + pq * 4);
    float4 pv = *(const float4*)(pos + (long)c * 65536 + pq * 4);
    float w0 = w[c * 2], w1 = w[c * 2 + 1], bc = b[c];
    uint4 o;
    o.x = splitf((w0 * x0.x + w1 * x1.x + bc) * 8.0f + pv.x);
    o.y = splitf((w0 * x0.y + w1 * x1.y + bc) * 8.0f + pv.y);
    o.z = splitf((w0 * x0.z + w1 * x1.z + bc) * 8.0f + pv.z);
    o.w = splitf((w0 * x0.w + w1 * x1.w + bc) * 8.0f + pv.w);
    *(uint4*)(h + t * 4) = o;
}

// ---------------------------------------------------------------- fused MLP: t2 = W2*silu(W1*h+b1)+b2
// R7-verified version (passed, 112us). Weight-fragment reuse across 4 M-tiles is
// the key property (R9's per-px partition broke it: 285us). mlp is parked here.
__global__ __launch_bounds__(256, 2)
void mlp_fused(const unsigned* __restrict__ Ax, const unsigned* __restrict__ W1x,
               const float* __restrict__ b1, const unsigned* __restrict__ W2x,
               const float* __restrict__ b2, float* __restrict__ t2) {
    __shared__ unsigned SM[12800];
    unsigned* ALDS = SM;            // A[px][132]  (k-padded, b128-aligned)
    unsigned* HLDS = SM + 8448;     // hidden[px][68]
    int tid = threadIdx.x;
    int w = tid >> 6, l = tid & 63;
    int lr = l & 15, lg = l >> 4;
    int p0 = blockIdx.x * 64;

    // ---- stage A (split h) into LDS, transposed to px-major
#pragma unroll
    for (int i = 0; i < 8; i++) {
        int f = i * 256 + tid;           // 0..2047
        int k = f >> 4, q = f & 15;      // k: 0..127 ch, q: 0..15 px-quad
        uint4 v = *(const uint4*)(Ax + (long)k * 65536 + p0 + q * 4);
        ALDS[(q * 4 + 0) * 132 + k] = v.x;
        ALDS[(q * 4 + 1) * 132 + k] = v.y;
        ALDS[(q * 4 + 2) * 132 + k] = v.z;
        ALDS[(q * 4 + 3) * 132 + k] = v.w;
    }
    __syncthreads();

    f32x4 acc2[4][2] = {};
#pragma unroll 1
    for (int c = 0; c < 8; c++) {
        // ---- gemm1: hidden chunk (64 wide) = A * W1[c*64..+64]^T ; wave owns 16 hid
        f32x4 acc1[4] = {};
#pragma unroll
        for (int ks = 0; ks < 4; ks++) {
            bf16x8 bh, bl;
            {
                const unsigned* bp = W1x + (c * 64 + w * 16 + lr) * 128 + ks * 32 + lg * 8;
                i32x4 d0 = *(const i32x4*)bp;
                i32x4 d1 = *(const i32x4*)(bp + 4);
                unpack2(d0, d1, bh, bl);
            }
#pragma unroll
            for (int ms = 0; ms < 4; ms++) {
                const i32x4* apx = (const i32x4*)&ALDS[(ms * 16 + lr) * 132 + ks * 32 + lg * 8];
                i32x4 a0 = apx[0], a1 = apx[1];
                bf16x8 ah, al; unpack2(a0, a1, ah, al);
                acc1[ms] = __builtin_amdgcn_mfma_f32_16x16x32_bf16(ah, bh, acc1[ms], 0, 0, 0);
                acc1[ms] = __builtin_amdgcn_mfma_f32_16x16x32_bf16(ah, bl, acc1[ms], 0, 0, 0);
                acc1[ms] = __builtin_amdgcn_mfma_f32_16x16x32_bf16(al, bh, acc1[ms], 0, 0, 0);
            }
        }
        // ---- silu + split -> HLDS[pix][68] (chunk-local hid index)
        {
            int hl = w * 16 + lr;
            float bias = b1[c * 64 + hl];
#pragma unroll
            for (int ms = 0; ms < 4; ms++)
#pragma unroll
                for (int r = 0; r < 4; r++) {
                    float pre = acc1[ms][r] + bias;
                    float s = pre / (1.0f + __expf(-pre));
                    int pix = ms * 16 + lg * 4 + r;
                    HLDS[pix * 68 + hl] = splitf(s);
                }
        }
        __syncthreads();
        // ---- gemm2 partial: acc2 += hidden * W2[:, c*64..+64]^T
#pragma unroll
        for (int ks2 = 0; ks2 < 2; ks2++) {
            bf16x8 bh[2], bl[2];
#pragma unroll
            for (int ns = 0; ns < 2; ns++) {
                const unsigned* bp = W2x + (w * 32 + ns * 16 + lr) * 512 + c * 64 + ks2 * 32 + lg * 8;
                i32x4 d0 = *(const i32x4*)bp;
                i32x4 d1 = *(const i32x4*)(bp + 4);
                unpack2(d0, d1, bh[ns], bl[ns]);
            }
#pragma unroll
            for (int ms = 0; ms < 4; ms++) {
                const i32x4* hp = (const i32x4*)&HLDS[(ms * 16 + lr) * 68 + ks2 * 32 + lg * 8];
                i32x4 d0 = hp[0], d1 = hp[1];
                bf16x8 ah, al; unpack2(d0, d1, ah, al);
#pragma unroll
                for (int ns = 0; ns < 2; ns++) {
                    acc2[ms][ns] = __builtin_amdgcn_mfma_f32_16x16x32_bf16(ah, bh[ns], acc2[ms][ns], 0, 0, 0);
                    acc2[ms][ns] = __builtin_amdgcn_mfma_f32_16x16x32_bf16(ah, bl[ns], acc2[ms][ns], 0, 0, 0);
                    acc2[ms][ns] = __builtin_amdgcn_mfma_f32_16x16x32_bf16(al, bh[ns], acc2[ms][ns], 0, 0, 0);
                }
            }
        }
        __syncthreads();
    }
    // ---- epilogue: T[n][68] (overlays A+hidden, both dead) then coalesced c-major store
    float* T = (float*)SM;
#pragma unroll
    for (int ns = 0; ns < 2; ns++) {
        int n = w * 32 + ns * 16 + lr;
        float bias = b2[n];
#pragma unroll
        for (int ms = 0; ms < 4; ms++)
#pragma unroll
            for (int r = 0; r < 4; r++) {
                int pix = ms * 16 + lg * 4 + r;
                T[n * 68 + pix] = acc2[ms][ns][r] + bias;
            }
    }
    __syncthreads();
#pragma unroll
    for (int i = 0; i < 8; i++) {
        int f = i * 256 + tid;             // 0..2047 float4s
        int n = f >> 4, q = f & 15;
        float4 v = *(const float4*)&T[n * 68 + q * 4];
        *(float4*)(t2 + (long)n * 65536 + p0 + q * 4) = v;
    }
}

// ---------------------------------------------------------------- OXO: h += t2*W^T + b (h split)
__global__ __launch_bounds__(256, 2)
void oxo_kernel(const unsigned* __restrict__ Tx, const unsigned* __restrict__ Bx,
                const float* __restrict__ ob, unsigned* __restrict__ h) {
    __shared__ float T[128 * 128];
    int tid = threadIdx.x;
    int w = tid >> 6, l = tid & 63;
    int lr = l & 15, lg = l >> 4;
    int m0 = blockIdx.x * 128;
    int n0 = w * 32;
    f32x4 acc[8][2] = {};
    for (int k0 = 0; k0 < 128; k0 += 32) {
        bf16x8 bh[2], bl[2];
#pragma unroll
        for (int ns = 0; ns < 2; ns++) {
            const unsigned* bp = Bx + (n0 + ns * 16 + lr) * 128 + k0 + lg * 8;
            i32x4 d0 = *(const i32x4*)bp;
            i32x4 d1 = *(const i32x4*)(bp + 4);
            unpack2(d0, d1, bh[ns], bl[ns]);
        }
#pragma unroll
        for (int ms = 0; ms < 8; ms++) {
            const unsigned* ap = Tx + (long)(k0 + lg * 8) * 65536 + m0 + ms * 16 + lr;
            int d[8];
#pragma unroll
            for (int j = 0; j < 8; j++) d[j] = (int)ap[(long)j * 65536];
            bf16x8 ah, al; unpack8(d, ah, al);
#pragma unroll
            for (int ns = 0; ns < 2; ns++) {
                acc[ms][ns] = __builtin_amdgcn_mfma_f32_16x16x32_bf16(ah, bh[ns], acc[ms][ns], 0, 0, 0);
                acc[ms][ns] = __builtin_amdgcn_mfma_f32_16x16x32_bf16(ah, bl[ns], acc[ms][ns], 0, 0, 0);
                acc[ms][ns] = __builtin_amdgcn_mfma_f32_16x16x32_bf16(al, bh[ns], acc[ms][ns], 0, 0, 0);
            }
        }
    }
#pragma unroll
    for (int ns = 0; ns < 2; ns++) {
        int n = n0 + ns * 16 + lr;
#pragma unroll
        for (int ms = 0; ms < 8; ms++) {
            int blk = ((ms * 4 + lg) + n) & 31;
#pragma unroll
            for (int r = 0; r < 4; r++)
                T[n * 128 + blk * 4 + r] = acc[ms][ns][r];
        }
    }
    __syncthreads();
#pragma unroll
    for (int i = 0; i < 16; i++) {
        int flat = i * 256 + tid;
        int n = flat >> 5, q = flat & 31;
        const float4* src = (const float4*)&T[n * 128 + (((q + n) & 31) * 4)];
        float4 v = *src;
        float bias = ob[n];
        unsigned* hp = h + (long)n * 65536 + m0 + q * 4;
        uint4 hv = *(uint4*)hp;
        uint4 o;
        o.x = splitf(upk(hv.x) + v.x + bias);
        o.y = splitf(upk(hv.y) + v.y + bias);
        o.z = splitf(upk(hv.z) + v.z + bias);
        o.w = splitf(upk(hv.w) + v.w + bias);
        *(uint4*)hp = o;
    }
}

// ---------------------------------------------------------------- row forward rfft, CHANNEL-PAIR, RADIX-4
// z = ch_a + i*ch_b; radix-4 Stockham (4 stages, m=1,4,16,64), exact composition
// of the verified radix-2 stage pairs (m,2m):
//  t0=a+c t1=W^jm4(a-c) t2=b+d t3=-i W^jm4(b-d); out[4jm4+r+{0,m,2m,3m}] =
//  {t0+t2, t1+t3, W^2jm4(t0-t2), W^2jm4(t1-t3)}.
__global__ void fft_row_fwd(const float* __restrict__ in, float2* __restrict__ freq, int c0) {
    __shared__ float2 A[4][256];
    __shared__ float2 B[4][256];
    __shared__ float2 TW[128];
    int tid = threadIdx.x;
    int pr = blockIdx.x >> 6, rgrp = blockIdx.x & 63;   // pr: channel pair 0..31
    if (tid < 128) {
        float sn, cs; __sincosf((PI2 / 256.f) * (float)tid, &sn, &cs);
        TW[tid] = make_float2(cs, sn);
    }
    {
        int r = tid >> 6, l = tid & 63;
        int row = rgrp * 4 + r;
        const float4* sa = (const float4*)(in + ((long)(c0 + pr * 2 + 0) * 256 + row) * 256);
        const float4* sb = (const float4*)(in + ((long)(c0 + pr * 2 + 1) * 256 + row) * 256);
        float4 va = sa[l], vb = sb[l];
        A[r][l * 4 + 0] = make_float2(va.x, vb.x);
        A[r][l * 4 + 1] = make_float2(va.y, vb.y);
        A[r][l * 4 + 2] = make_float2(va.z, vb.z);
        A[r][l * 4 + 3] = make_float2(va.w, vb.w);
    }
    __syncthreads();
    float2 (*s)[256] = A; float2 (*d)[256] = B;
    int rr = tid >> 6, u = tid & 63;
    for (int m = 1; m < 256; m <<= 2) {
        int jm4 = u & ~(m - 1);
        float2 a = s[rr][u], b = s[rr][u + 64], c = s[rr][u + 128], e = s[rr][u + 192];
        float2 w1 = TW[jm4], w2 = TW[2 * jm4];
        float2 t0 = cadd(a, c);
        float2 t1 = cmulf(w1, csub(a, c));
        float2 t2 = cadd(b, e);
        float2 t3p = cmulf(w1, csub(b, e));
        float2 t3 = make_float2(t3p.y, -t3p.x);        // * -i
        int base = 4 * jm4 + (u - jm4);
        d[rr][base]         = cadd(t0, t2);
        d[rr][base + m]     = cadd(t1, t3);
        d[rr][base + 2 * m] = cmulf(w2, csub(t0, t2));
        d[rr][base + 3 * m] = cmulf(w2, csub(t1, t3));
        __syncthreads();
        float2 (*tmp)[256] = s; s = d; d = tmp;
    }
    long iba = (long)(pr * 2 + 0) * 34816;
    long ibb = (long)(pr * 2 + 1) * 34816;
    for (int q = tid; q < 4 * 129; q += 256) {
        int r = q / 129; int k = q - r * 129;
        float2 z  = s[r][k];
        float2 zm = s[r][(256 - k) & 255];
        float2 za = make_float2(0.5f * (z.x + zm.x), 0.5f * (z.y - zm.y));
        float2 zb = make_float2(0.5f * (z.y + zm.y), 0.5f * (zm.x - z.x));
        long off = (k >> 3) * 2048 + (rgrp * 4 + r) * 8 + (k & 7);
        freq[iba + off] = za;
        freq[ibb + off] = zb;
    }
}

// ---------------------------------------------------------------- column FFT + filter + inverse, RADIX-4
__global__ void fft_col(float2* __restrict__ freq, const float* __restrict__ mags,
                        const float* __restrict__ phases, int c0) {
    __shared__ float2 A[8][256];
    __shared__ float2 B[8][256];
    __shared__ float2 TW[128];
    int tid = threadIdx.x;
    int img = blockIdx.x / 17;
    int kt  = blockIdx.x % 17;
    int kx0 = kt * 8;
    float2* base = freq + (long)img * 34816 + kt * 2048;
    if (tid < 128) {
        float sn, cs; __sincosf((PI2 / 256.f) * (float)tid, &sn, &cs);
        TW[tid] = make_float2(cs, sn);
    }
#pragma unroll
    for (int q = 0; q < 8; q++) {
        int e = tid + q * 256;
        A[e & 7][e >> 3] = base[e];       // fully contiguous 16 KB
    }
    __syncthreads();
    float2 (*s)[256] = A; float2 (*d)[256] = B;
    for (int m = 1; m < 256; m <<= 2) {           // forward radix-4
#pragma unroll
        for (int q2 = 0; q2 < 2; q2++) {
            int bf = tid + q2 * 256;              // 0..511 = 8 cols x 64
            int cl = bf >> 6, u = bf & 63;
            int jm4 = u & ~(m - 1);
            float2 a = s[cl][u], b = s[cl][u + 64], c = s[cl][u + 128], e = s[cl][u + 192];
            float2 w1 = TW[jm4], w2 = TW[2 * jm4];
            float2 t0 = cadd(a, c);
            float2 t1 = cmulf(w1, csub(a, c));
            float2 t2 = cadd(b, e);
            float2 t3p = cmulf(w1, csub(b, e));
            float2 t3 = make_float2(t3p.y, -t3p.x);    // * -i
            int bs = 4 * jm4 + (u - jm4);
            d[cl][bs]         = cadd(t0, t2);
            d[cl][bs + m]     = cadd(t1, t3);
            d[cl][bs + 2 * m] = cmulf(w2, csub(t0, t2));
            d[cl][bs + 3 * m] = cmulf(w2, csub(t1, t3));
        }
        __syncthreads();
        float2 (*tmp)[256] = s; s = d; d = tmp;
    }
#pragma unroll
    for (int q = 0; q < 8; q++) {
        int e = tid + q * 256;
        int cl = e & 7, ky = e >> 3;
        int kx = kx0 + cl;
        float2 v = s[cl][ky];
        float2 r = make_float2(0.f, 0.f);
        if (kx < 129) {
            int ry = ky < 128 ? ky : ky - 256;
            if (kx * kx + ry * ry <= 16384) {
                long fi = ((long)(c0 + img) * 256 + ky) * 129 + kx;
                float mg = mags[fi], ph = phases[fi];
                float sg = 1.0f / (1.0f + __expf(-mg));
                float sn, cs; __sincosf(ph, &sn, &cs);
                float fr = sg * cs, fim = sg * sn;
                r = make_float2(v.x * fr - v.y * fim, v.x * fim + v.y * fr);
            }
        }
        s[cl][ky] = r;
    }
    __syncthreads();
    for (int m = 1; m < 256; m <<= 2) {           // inverse radix-4
#pragma unroll
        for (int q2 = 0; q2 < 2; q2++) {
            int bf = tid + q2 * 256;
            int cl = bf >> 6, u = bf & 63;
            int jm4 = u & ~(m - 1);
            float2 a = s[cl][u], b = s[cl][u + 64], c = s[cl][u + 128], e = s[cl][u + 192];
            float2 w1 = TW[jm4], w2 = TW[2 * jm4];
            float2 t0 = cadd(a, c);
            float2 t1 = cmuli(w1, csub(a, c));
            float2 t2 = cadd(b, e);
            float2 t3p = cmuli(w1, csub(b, e));
            float2 t3 = make_float2(-t3p.y, t3p.x);    // * +i
            int bs = 4 * jm4 + (u - jm4);
            d[cl][bs]         = cadd(t0, t2);
            d[cl][bs + m]     = cadd(t1, t3);
            d[cl][bs + 2 * m] = cmuli(w2, csub(t0, t2));
            d[cl][bs + 3 * m] = cmuli(w2, csub(t1, t3));
        }
        __syncthreads();
        float2 (*tmp)[256] = s; s = d; d = tmp;
    }
#pragma unroll
    for (int q = 0; q < 8; q++) {
        int e = tid + q * 256;
        base[e] = s[e & 7][e >> 3];
    }
}

// ---------------------------------------------------------------- row inverse rfft, CHANNEL-PAIR, RADIX-4
// Z'[k] = G_a[k] + i*G_b[k] (Hermitian-extended) -> one inverse FFT; Re->a, Im->b.
// CRITICAL: numpy irfft ignores Im of DC/Nyquist bins -> zero them on load.
__global__ void fft_row_inv(const float2* __restrict__ freq, unsigned* __restrict__ out, int c0) {
    __shared__ float2 A[4][256];
    __shared__ float2 B[4][256];
    __shared__ float2 TW[128];
    int tid = threadIdx.x;
    int pr = blockIdx.x >> 6, rgrp = blockIdx.x & 63;
    if (tid < 128) {
        float sn, cs; __sincosf((PI2 / 256.f) * (float)tid, &sn, &cs);
        TW[tid] = make_float2(cs, sn);
    }
    long iba = (long)(pr * 2 + 0) * 34816;
    long ibb = (long)(pr * 2 + 1) * 34816;
#pragma unroll
    for (int q = 0; q < 4; q++) {
        int e = tid + q * 256;
        int r = e >> 8, xx = e & 255;
        int k = (xx <= 128) ? xx : 256 - xx;
        long off = (k >> 3) * 2048 + (rgrp * 4 + r) * 8 + (k & 7);
        float2 ga = freq[iba + off];
        float2 gb = freq[ibb + off];
        if (k == 0 || k == 128) { ga.y = 0.f; gb.y = 0.f; }   // irfft c2r semantics
        float2 v;
        if (xx <= 128) v = make_float2(ga.x - gb.y, ga.y + gb.x);          // Ga + i*Gb
        else           v = make_float2(ga.x + gb.y, gb.x - ga.y);          // conj(Ga) + i*conj(Gb)
        A[r][xx] = v;
    }
    __syncthreads();
    float2 (*s)[256] = A; float2 (*d)[256] = B;
    int rr = tid >> 6, u = tid & 63;
    for (int m = 1; m < 256; m <<= 2) {
        int jm4 = u & ~(m - 1);
        float2 a = s[rr][u], b = s[rr][u + 64], c = s[rr][u + 128], e = s[rr][u + 192];
        float2 w1 = TW[jm4], w2 = TW[2 * jm4];
        float2 t0 = cadd(a, c);
        float2 t1 = cmuli(w1, csub(a, c));
        float2 t2 = cadd(b, e);
        float2 t3p = cmuli(w1, csub(b, e));
        float2 t3 = make_float2(-t3p.y, t3p.x);        // * +i
        int base = 4 * jm4 + (u - jm4);
        d[rr][base]         = cadd(t0, t2);
        d[rr][base + m]     = cadd(t1, t3);
        d[rr][base + 2 * m] = cmuli(w2, csub(t0, t2));
        d[rr][base + 3 * m] = cmuli(w2, csub(t1, t3));
        __syncthreads();
        float2 (*tmp)[256] = s; s = d; d = tmp;
    }
    {
        int r = tid >> 6, l = tid & 63;
        const float sc = 1.0f / 65536.0f;
        int row = rgrp * 4 + r;
        uint4 oa, ob;
        oa.x = splitf(s[r][l * 4 + 0].x * sc);
        oa.y = splitf(s[r][l * 4 + 1].x * sc);
        oa.z = splitf(s[r][l * 4 + 2].x * sc);
        oa.w = splitf(s[r][l * 4 + 3].x * sc);
        ob.x = splitf(s[r][l * 4 + 0].y * sc);
        ob.y = splitf(s[r][l * 4 + 1].y * sc);
        ob.z = splitf(s[r][l * 4 + 2].y * sc);
        ob.w = splitf(s[r][l * 4 + 3].y * sc);
        *(uint4*)(out + ((long)(c0 + pr * 2 + 0) * 256 + row) * 256 + l * 4) = oa;
        *(uint4*)(out + ((long)(c0 + pr * 2 + 1) * 256 + row) * 256 + l * 4) = ob;
    }
}

// ---------------------------------------------------------------- decoder (h split)
__global__ void dec_kernel(const unsigned* __restrict__ h, const float* __restrict__ w,
                           const float* __restrict__ b, float* __restrict__ out) {
    int t = blockIdx.x * 256 + threadIdx.x;
    int bb = t >> 16, p = t & 65535;
    const unsigned* hb = h + (long)bb * 8388608 + p;
    float a0 = b[0], a1 = b[1];
    float a0b = 0.f, a1b = 0.f;
#pragma unroll 4
    for (int c = 0; c < 128; c += 2) {
        float h0 = upk(hb[(long)c * 65536]);
        float h1 = upk(hb[(long)(c + 1) * 65536]);
        a0  += w[c] * h0;        a1  += w[128 + c] * h0;
        a0b += w[c + 1] * h1;    a1b += w[128 + c + 1] * h1;
    }
    out[((long)bb * 2 + 0) * 65536 + p] = (a0 + a0b) * 0.125f;
    out[((long)bb * 2 + 1) * 65536 + p] = (a1 + a1b) * 0.125f;
}

// ---------------------------------------------------------------- launch
extern "C" void kernel_launch(void* const* d_in, const int* in_sizes, int n_in,
                              void* d_out, int out_size, void* d_ws, size_t ws_size,
                              hipStream_t stream) {
    const float* x        = (const float*)d_in[0];
    const float* enc_w    = (const float*)d_in[1];
    const float* enc_b    = (const float*)d_in[2];
    const float* pos_emb  = (const float*)d_in[3];
    const float* mlp_w1   = (const float*)d_in[4];
    const float* mlp_b1   = (const float*)d_in[5];
    const float* mlp_w2   = (const float*)d_in[6];
    const float* mlp_b2   = (const float*)d_in[7];
    const float* spec_mag = (const float*)d_in[8];
    const float* spec_ph  = (const float*)d_in[9];
    const float* oxo_w    = (const float*)d_in[10];
    const float* oxo_b    = (const float*)d_in[11];
    const float* dec_w    = (const float*)d_in[12];
    const float* dec_b    = (const float*)d_in[13];
    float* outp = (float*)d_out;

    // ws layout (dwords):
    //  h (split)      33,554,432
    //  t2 / TxO        8,388,608
    //  freq (64ch)     4,456,448   ([img64][kt17][y256][kx8] float2)
    //  Wx1/Wx2/Wox       147,456
    //  total          46,546,944 dw = 186,187,776 B
    const size_t WS_NEEDED = 186187776ULL;
    if (ws_size < WS_NEEDED) {
        sentinel_kernel<<<(out_size + 255) / 256, 256, 0, stream>>>(outp, out_size);
        return;
    }

    unsigned* u    = (unsigned*)d_ws;
    unsigned* h    = u;
    float*    t2   = (float*)(u + 33554432);
    unsigned* TxO  = (unsigned*)t2;
    float2*   freq = (float2*)(u + 41943040);
    unsigned* Wx1  = u + 46399488;
    unsigned* Wx2  = Wx1 + 65536;
    unsigned* Wox  = Wx2 + 65536;

    enc_kernel<<<32768, 256, 0, stream>>>(x, enc_w, enc_b, pos_emb, h);

    for (int l = 0; l < 4; l++) {
        split_kernel<<<64, 256, 0, stream>>>(mlp_w1 + (long)l * 65536, Wx1);
        split_kernel<<<64, 256, 0, stream>>>(mlp_w2 + (long)l * 65536, Wx2);
        split_kernel<<<16, 256, 0, stream>>>(oxo_w + (long)l * 16384, Wox);
        const float* b1l = mlp_b1 + l * 512;
        const float* b2l = mlp_b2 + l * 128;
        const float* mgl = spec_mag + (long)l * 4227072;
        const float* phl = spec_ph  + (long)l * 4227072;
        const float* obl = oxo_b + l * 128;
        for (int b = 0; b < 4; b++) {
            unsigned* hb = h + (long)b * 8388608;
            mlp_fused<<<1024, 256, 0, stream>>>(hb, Wx1, b1l, Wx2, b2l, t2);
            for (int c0 = 0; c0 < 128; c0 += 64) {
                fft_row_fwd<<<2048, 256, 0, stream>>>(t2, freq, c0);
                fft_col<<<64 * 17, 256, 0, stream>>>(freq, mgl, phl, c0);
                fft_row_inv<<<2048, 256, 0, stream>>>(freq, TxO, c0);
            }
            oxo_kernel<<<512, 256, 0, stream>>>(TxO, Wox, obl, hb);
        }
    }

    dec_kernel<<<1024, 256, 0, stream>>>(h, dec_w, dec_b, outp);
}